// Round 8
// baseline (693.593 us; speedup 1.0000x reference)
//
#include <hip/hip_runtime.h>
#include <hip/hip_bf16.h>

// ---------------------------------------------------------------------------
// VQ-VAE forward. GEMM operands pre-tiled to MFMA layout [panel][kbg][128][8],
// staged via global_load_lds dwordx4. Encoder split-bf16 (3-MFMA), decoder
// plain bf16. Round 8: identical resubmit of round 7 (GPU acquisition
// timeout — no kernel verdict).
// ---------------------------------------------------------------------------

typedef __attribute__((ext_vector_type(8))) short short8v;
typedef __attribute__((ext_vector_type(4))) float f32x4;

__device__ inline ushort f2bf(float v) {
    __hip_bfloat16 h = __float2bfloat16(v);
    return *reinterpret_cast<ushort*>(&h);
}
__device__ inline float bf2f(ushort s) {
    __hip_bfloat16 h;
    *reinterpret_cast<ushort*>(&h) = s;
    return __bfloat162float(h);
}

// copy 8192 B (one K-step tile) global -> LDS; layouts identical (linear DMA).
__device__ __forceinline__ void stage_tile(const ushort* __restrict__ src,
                                           ushort* dst, int wid, int lane)
{
#pragma unroll
    for (int j = 0; j < 2; ++j) {
        const int ci = (j << 2) + wid;
        __builtin_amdgcn_global_load_lds(
            (const __attribute__((address_space(1))) unsigned int*)(src + ci * 512 + lane * 8),
            (__attribute__((address_space(3))) unsigned int*)(dst + ci * 512),
            16, 0, 0);
    }
}

// ---------------------------------------------------------------------------
// MFMA GEMM on tiled operands (unchanged from round 6; at m97-structure
// ceiling: 870 TF effective, MfmaUtil 37%).
// ---------------------------------------------------------------------------
template<int ACT, bool SPLIT, int OMODE>
__global__ __launch_bounds__(256)
void gemm_mfma(const ushort* __restrict__ At, const ushort* __restrict__ Alt,
               const ushort* __restrict__ Bt, const ushort* __restrict__ Blt,
               const float* __restrict__ bias,
               float* __restrict__ Cf, ushort* __restrict__ Chi, ushort* __restrict__ Clo,
               int kbgA, int nsteps, int N)
{
    __shared__ short8v AhV[512];
    __shared__ short8v BhV[512];
    __shared__ short8v AlV[SPLIT ? 512 : 1];
    __shared__ short8v BlV[SPLIT ? 512 : 1];
    ushort* Ah = (ushort*)AhV;
    ushort* Bh = (ushort*)BhV;
    ushort* Al = (ushort*)AlV;
    ushort* Bl = (ushort*)BlV;

    const int tid  = threadIdx.x;
    const int lane = tid & 63;
    const int wid  = tid >> 6;
    const int wr   = (wid >> 1) * 64;
    const int wc   = (wid & 1) * 64;

    const int flat = blockIdx.y * gridDim.x + blockIdx.x;
    const int cpx  = (gridDim.x * gridDim.y) >> 3;
    const int swz  = (flat & 7) * cpx + (flat >> 3);
    const int cb   = swz % gridDim.x;
    const int rb   = swz / gridDim.x;
    const int row0 = rb * 128;
    const int col0 = cb * 128;

    f32x4 acc[4][4];
#pragma unroll
    for (int m = 0; m < 4; ++m)
#pragma unroll
        for (int n = 0; n < 4; ++n) acc[m][n] = (f32x4){0.f, 0.f, 0.f, 0.f};

    const int fr = lane & 15;
    const int kq = lane >> 4;

    const size_t abase = (size_t)rb * kbgA * 1024;
    const size_t bbase = (size_t)cb * kbgA * 1024;

    for (int s = 0; s < nsteps; ++s) {
        const size_t off = (size_t)s * 4096;
        stage_tile(At + abase + off, Ah, wid, lane);
        stage_tile(Bt + bbase + off, Bh, wid, lane);
        if (SPLIT) {
            stage_tile(Alt + abase + off, Al, wid, lane);
            stage_tile(Blt + bbase + off, Bl, wid, lane);
        }
        __syncthreads();

        short8v a_h[4], b_h[4], a_l[4], b_l[4];
#pragma unroll
        for (int m = 0; m < 4; ++m) {
            a_h[m] = *(const short8v*)&Ah[kq * 1024 + (wr + m * 16 + fr) * 8];
            if (SPLIT) a_l[m] = *(const short8v*)&Al[kq * 1024 + (wr + m * 16 + fr) * 8];
        }
#pragma unroll
        for (int n = 0; n < 4; ++n) {
            b_h[n] = *(const short8v*)&Bh[kq * 1024 + (wc + n * 16 + fr) * 8];
            if (SPLIT) b_l[n] = *(const short8v*)&Bl[kq * 1024 + (wc + n * 16 + fr) * 8];
        }
#pragma unroll
        for (int m = 0; m < 4; ++m)
#pragma unroll
            for (int n = 0; n < 4; ++n) {
                acc[m][n] = __builtin_amdgcn_mfma_f32_16x16x32_bf16(a_h[m], b_h[n], acc[m][n], 0, 0, 0);
                if (SPLIT) {
                    acc[m][n] = __builtin_amdgcn_mfma_f32_16x16x32_bf16(a_h[m], b_l[n], acc[m][n], 0, 0, 0);
                    acc[m][n] = __builtin_amdgcn_mfma_f32_16x16x32_bf16(a_l[m], b_h[n], acc[m][n], 0, 0, 0);
                }
            }
        __syncthreads();
    }

    const int kbgN = gridDim.x << 4;
#pragma unroll
    for (int n = 0; n < 4; ++n) {
        const int c = col0 + wc + n * 16 + fr;
        const float bv = (bias && c < N) ? bias[c] : 0.f;
#pragma unroll
        for (int m = 0; m < 4; ++m) {
#pragma unroll
            for (int i = 0; i < 4; ++i) {
                const int r = row0 + wr + m * 16 + kq * 4 + i;
                float v = acc[m][n][i] + bv;
                if (ACT == 1) v = fmaxf(v, 0.f);
                else if (ACT == 2) v = (v > 0.f) ? v : 0.1f * v;
                else if (ACT == 3) v = tanhf(v);
                if (OMODE == 0) {
                    if (c < N) Cf[(size_t)r * N + c] = v;
                } else {
                    if (c >= N) v = 0.f;
                    const size_t oi = (((size_t)(r >> 7) * kbgN + (c >> 3)) * 128 + (r & 127)) * 8 + (c & 7);
                    const ushort h = f2bf(v);
                    Chi[oi] = h;
                    if (OMODE == 2) Clo[oi] = f2bf(v - bf2f(h));
                }
            }
        }
    }
}

// sum of squares per row of 64 floats (E only now)
__global__ void row_norms64(const float* __restrict__ X, float* __restrict__ out, int rows)
{
    int r = blockIdx.x * blockDim.x + threadIdx.x;
    if (r >= rows) return;
    const float* p = X + (size_t)r * 64;
    float s = 0.f;
#pragma unroll
    for (int i = 0; i < 16; ++i) {
        float4 v = *reinterpret_cast<const float4*>(p + i * 4);
        s += v.x * v.x + v.y * v.y + v.z * v.z + v.w * v.w;
    }
    out[r] = s;
}

// ---------------------------------------------------------------------------
// Fused nearest-neighbor: no S matrix.
// 256 blocks x 256 threads; block b owns rows r0=64b..+64 (row = lane).
// Wave w covers cols {c0 + 32w .. +32} per 128-col chunk.
// Row argmin (=> Zdec, Zdcb gather) done fully in-block; column argmin
// emits per-block partials Pv/Pi[512][256] reduced by argmin_cols_p2.
// Distances: v_row = En2[k] - 2*dot, v_col = Zn2[r] - 2*dot (f32 FMA chains);
// ties: ascending-scan first-min + lexicographic (val, idx) combines.
// ---------------------------------------------------------------------------
__global__ __launch_bounds__(256)
void fused_nn(const float* __restrict__ Zenc, const float* __restrict__ E,
              const float* __restrict__ En2,
              float* __restrict__ Zdec, ushort* __restrict__ Zdcb,
              float* __restrict__ Pv, int* __restrict__ Pi)
{
    const int b    = blockIdx.x;
    const int r0   = b << 6;
    const int tid  = threadIdx.x;
    const int lane = tid & 63;
    const int wu   = __builtin_amdgcn_readfirstlane(tid >> 6);  // wave id, SGPR

    __shared__ float Zl[64][65];
    __shared__ float rbv[4][64];
    __shared__ int   rbi[4][64];
    __shared__ int   widx[64];

    // stage Zenc tile (coalesced): thread t -> row t>>2, d-quarter (t&3)*16
    {
        const int r  = tid >> 2;
        const int dq = (tid & 3) << 4;
        const float* src = Zenc + (size_t)(r0 + r) * 64 + dq;
#pragma unroll
        for (int q = 0; q < 4; ++q) {
            float4 v = *(const float4*)(src + q * 4);
            Zl[r][dq + q * 4 + 0] = v.x;
            Zl[r][dq + q * 4 + 1] = v.y;
            Zl[r][dq + q * 4 + 2] = v.z;
            Zl[r][dq + q * 4 + 3] = v.w;
        }
    }
    __syncthreads();

    // per-lane row norm (row = lane); LDS reads 2 lanes/bank (free)
    float zn2 = 0.f;
#pragma unroll
    for (int d = 0; d < 64; ++d) zn2 += Zl[lane][d] * Zl[lane][d];

    float rbest = INFINITY;
    int   ridx  = 0x7fffffff;

    for (int c0 = 0; c0 < 512; c0 += 128) {
        const float* Ew = E + ((size_t)(c0 + (wu << 5)) << 6);  // wave-uniform

        float dot[32];
#pragma unroll
        for (int ki = 0; ki < 32; ++ki) dot[ki] = 0.f;

        for (int d0 = 0; d0 < 64; d0 += 16) {
            float zc[16];
#pragma unroll
            for (int q = 0; q < 16; ++q) zc[q] = Zl[lane][d0 + q];
#pragma unroll
            for (int ki = 0; ki < 32; ++ki) {
                const float4* er4 = (const float4*)(Ew + (ki << 6) + d0);
                const float4 e0 = er4[0], e1 = er4[1], e2 = er4[2], e3 = er4[3];
                dot[ki] = fmaf(zc[0],  e0.x, dot[ki]);
                dot[ki] = fmaf(zc[1],  e0.y, dot[ki]);
                dot[ki] = fmaf(zc[2],  e0.z, dot[ki]);
                dot[ki] = fmaf(zc[3],  e0.w, dot[ki]);
                dot[ki] = fmaf(zc[4],  e1.x, dot[ki]);
                dot[ki] = fmaf(zc[5],  e1.y, dot[ki]);
                dot[ki] = fmaf(zc[6],  e1.z, dot[ki]);
                dot[ki] = fmaf(zc[7],  e1.w, dot[ki]);
                dot[ki] = fmaf(zc[8],  e2.x, dot[ki]);
                dot[ki] = fmaf(zc[9],  e2.y, dot[ki]);
                dot[ki] = fmaf(zc[10], e2.z, dot[ki]);
                dot[ki] = fmaf(zc[11], e2.w, dot[ki]);
                dot[ki] = fmaf(zc[12], e3.x, dot[ki]);
                dot[ki] = fmaf(zc[13], e3.y, dot[ki]);
                dot[ki] = fmaf(zc[14], e3.z, dot[ki]);
                dot[ki] = fmaf(zc[15], e3.w, dot[ki]);
            }
        }

        // row argmin update (k ascending within the thread's subset)
        float cbv = 0.f; int cbi = 0;
#pragma unroll
        for (int ki = 0; ki < 32; ++ki) {
            const int k = c0 + (wu << 5) + ki;
            const float vr = En2[k] - 2.0f * dot[ki];
            if (vr < rbest) { rbest = vr; ridx = k; }
            // column partial: min over the block's 64 rows (wave = 64 rows)
            float vc = zn2 - 2.0f * dot[ki];
            int   ic = r0 + lane;
#pragma unroll
            for (int off = 32; off > 0; off >>= 1) {
                const float ov = __shfl_xor(vc, off);
                const int   oi = __shfl_xor(ic, off);
                if (ov < vc || (ov == vc && oi < ic)) { vc = ov; ic = oi; }
            }
            if (lane == ki) { cbv = vc; cbi = ic; }
        }
        if (lane < 32) {
            const int k = c0 + (wu << 5) + lane;
            Pv[(size_t)k * 256 + b] = cbv;
            Pi[(size_t)k * 256 + b] = cbi;
        }
    }

    // combine row bests across the 4 waves (lexicographic)
    rbv[tid >> 6][lane] = rbest;
    rbi[tid >> 6][lane] = ridx;
    __syncthreads();
    if (tid < 64) {
        float bv = rbv[0][tid]; int bi = rbi[0][tid];
#pragma unroll
        for (int w2 = 1; w2 < 4; ++w2) {
            const float v = rbv[w2][tid];
            const int   i = rbi[w2][tid];
            if (v < bv || (v == bv && i < bi)) { bv = v; bi = i; }
        }
        widx[tid] = bi;
    }
    __syncthreads();

    // gather winning E rows -> Zdec (f32) + Zdcb (tiled bf16 for dec1)
    {
        const int r  = tid >> 2;
        const int dq = (tid & 3) << 4;
        const int R  = r0 + r;
        const float* src = E + (size_t)widx[r] * 64 + dq;
#pragma unroll
        for (int q = 0; q < 4; ++q) {
            float4 v = *(const float4*)(src + q * 4);
            float* dst = Zdec + (size_t)R * 64 + dq + q * 4;
            *(float4*)dst = v;
            const float vv[4] = {v.x, v.y, v.z, v.w};
#pragma unroll
            for (int e = 0; e < 4; ++e) {
                const int d = dq + q * 4 + e;
                const size_t oi = (((size_t)(R >> 7) * 8 + (d >> 3)) * 128 + (R & 127)) * 8 + (d & 7);
                Zdcb[oi] = f2bf(vv[e]);
            }
        }
    }
}

// phase-2 column reduce over 256 block-partials + gather Zenc row
__global__ __launch_bounds__(256)
void argmin_cols_p2(const float* __restrict__ pval, const int* __restrict__ pidx,
                    const float* __restrict__ Zenc, float* __restrict__ Zemb)
{
    const int k   = blockIdx.x;
    const int tid = threadIdx.x;
    float v = pval[(size_t)k * 256 + tid];
    int   i = pidx[(size_t)k * 256 + tid];
    __shared__ float vs[256];
    __shared__ int   is_[256];
    vs[tid] = v; is_[tid] = i;
    __syncthreads();
    for (int s = 128; s > 0; s >>= 1) {
        if (tid < s) {
            if (vs[tid + s] < vs[tid] ||
                (vs[tid + s] == vs[tid] && is_[tid + s] < is_[tid])) {
                vs[tid] = vs[tid + s]; is_[tid] = is_[tid + s];
            }
        }
        __syncthreads();
    }
    const int idx = is_[0];
    if (tid < 64) Zemb[(size_t)k * 64 + tid] = Zenc[(size_t)idx * 64 + tid];
}

// X [16384][784] f32 -> tiled split bf16 [128 rb][100 kbg][128][8]
__global__ void conv_x(const float* __restrict__ X, ushort* __restrict__ hi,
                       ushort* __restrict__ lo)
{
    const long total = 128L * 100 * 1024;
    for (long idx = blockIdx.x * 256L + threadIdx.x; idx < total; idx += (long)gridDim.x * 256L) {
        const int j  = (int)(idx & 7);
        const long t = idx >> 3;
        const int rn = (int)(t & 127);
        const long u = t >> 7;
        const int kb = (int)(u % 100);
        const int rb = (int)(u / 100);
        const int r = rb * 128 + rn;
        const int k = kb * 8 + j;
        const float v = (k < 784) ? X[(size_t)r * 784 + k] : 0.f;
        const ushort h = f2bf(v);
        hi[idx] = h;
        lo[idx] = f2bf(v - bf2f(h));
    }
}

// ---------------------------------------------------------------------------
// merged weight prep: 8 segments (W1..W4 split, V1..V4 plain) in one launch.
// Each block does 1024 elements (256 thr x 4 consecutive = same (kb,n), j0..+3).
// ---------------------------------------------------------------------------
struct PrepAll {
    const float* W[8];
    ushort* hi[8];
    ushort* lo[8];
    int K[8], N[8], kbg[8];
    int blk0[9];
};

__global__ __launch_bounds__(256)
void prep_all(PrepAll P)
{
    const int bid = blockIdx.x;
    int s = 0;
#pragma unroll
    for (int i = 1; i < 8; ++i) if (bid >= P.blk0[i]) s = i;
    const int  K = P.K[s], N = P.N[s], kbg = P.kbg[s];
    const bool split = (s < 4);
    const float* W = P.W[s];
    ushort* hi = P.hi[s];
    ushort* lo = P.lo[s];

    const long idx = (long)(bid - P.blk0[s]) * 1024 + threadIdx.x * 4;
    const int j0 = (int)(idx & 7);
    const long t = idx >> 3;
    const int cn = (int)(t & 127);
    const long u = t >> 7;
    const int kb = (int)(u % kbg);
    const int p  = (int)(u / kbg);
    const int n  = p * 128 + cn;

    ushort hv[4], lv[4];
#pragma unroll
    for (int e = 0; e < 4; ++e) {
        const int k = kb * 8 + j0 + e;
        const float v = (k < K && n < N) ? W[(size_t)k * N + n] : 0.f;
        const ushort h = f2bf(v);
        hv[e] = h;
        lv[e] = f2bf(v - bf2f(h));
    }
    *(ushort4*)&hi[idx] = *(ushort4*)hv;
    if (split) *(ushort4*)&lo[idx] = *(ushort4*)lv;
}

extern "C" void kernel_launch(void* const* d_in, const int* in_sizes, int n_in,
                              void* d_out, int out_size, void* d_ws, size_t ws_size,
                              hipStream_t stream)
{
    const float* X  = (const float*)d_in[0];
    const float* W1 = (const float*)d_in[1];
    const float* b1 = (const float*)d_in[2];
    const float* W2 = (const float*)d_in[3];
    const float* b2 = (const float*)d_in[4];
    const float* W3 = (const float*)d_in[5];
    const float* b3 = (const float*)d_in[6];
    const float* W4 = (const float*)d_in[7];
    const float* b4 = (const float*)d_in[8];
    const float* E  = (const float*)d_in[9];
    const float* V1 = (const float*)d_in[10];
    const float* c1 = (const float*)d_in[11];
    const float* V2 = (const float*)d_in[12];
    const float* c2 = (const float*)d_in[13];
    const float* V3 = (const float*)d_in[14];
    const float* c3 = (const float*)d_in[15];
    const float* V4 = (const float*)d_in[16];
    const float* c4 = (const float*)d_in[17];

    float* out  = (float*)d_out;
    float* Xrec = out;                  // 16384*784
    float* Zenc = out + 12845056;
    float* Zdec = out + 13893632;
    float* Zemb = out + 14942208;

    // ---- workspace layout (peak ~98.9 MB; >=118 MB proven) ----
    char* ws = (char*)d_ws;
    ushort* Xhi = (ushort*)(ws + 0);           // 26,214,400
    ushort* Xlo = (ushort*)(ws + 26214400);
    ushort* h2h = (ushort*)(ws + 0);           // after enc1
    ushort* h2l = (ushort*)(ws + 16777216);
    ushort* g3  = (ushort*)(ws + 0);           // after fused_nn (h2 dead)
    ushort* h1l = (ushort*)(ws + 52428800);
    ushort* h3h = (ushort*)(ws + 52428800);    // after enc2
    ushort* h3l = (ushort*)(ws + 65011712);
    ushort* g1  = (ushort*)(ws + 52428800);    // after enc4
    ushort* g2  = (ushort*)(ws + 65011712);
    ushort* h1h = (ushort*)d_out;              // parks in Xrec slab
    float*  En2  = (float*)(ws + 86048768);
    ushort* Zdcb = (ushort*)(ws + 86050816);
    ushort* Wt1h = (ushort*)(ws + 88147968);
    ushort* Wt1l = (ushort*)(ws + 89786368);
    ushort* Wt2h = (ushort*)(ws + 91424768);
    ushort* Wt2l = (ushort*)(ws + 92473344);
    ushort* Wt3h = (ushort*)(ws + 93521920);
    ushort* Wt3l = (ushort*)(ws + 93915136);
    ushort* Wt4h = (ushort*)(ws + 94308352);
    ushort* Wt4l = (ushort*)(ws + 94406656);
    ushort* Vt1  = (ushort*)(ws + 94504960);
    ushort* Vt2  = (ushort*)(ws + 94554112);
    ushort* Vt3  = (ushort*)(ws + 94947328);
    ushort* Vt4  = (ushort*)(ws + 95995904);
    float*  Pv   = (float*)(ws + 97830912);    // [512][256]
    int*    Pi   = (int*)  (ws + 98355200);

    const dim3 blk(256);

    // ---- conversion & tiling ----
    conv_x<<<dim3(2048), blk, 0, stream>>>(X, Xhi, Xlo);
    {
        PrepAll P;
        const float* Wl[8] = {W1, W2, W3, W4, V1, V2, V3, V4};
        ushort* Hl[8] = {Wt1h, Wt2h, Wt3h, Wt4h, Vt1, Vt2, Vt3, Vt4};
        ushort* Ll[8] = {Wt1l, Wt2l, Wt3l, Wt4l, nullptr, nullptr, nullptr, nullptr};
        const int Kl[8]   = {784, 1000, 500, 300, 64, 300, 500, 1000};
        const int Nl[8]   = {1000, 500, 300, 64, 300, 500, 1000, 784};
        const int KBl[8]  = {100, 128, 64, 48, 8, 48, 64, 128};
        const int NPl[8]  = {8, 4, 3, 1, 3, 4, 8, 7};
        int acc = 0;
        for (int i = 0; i < 8; ++i) {
            P.W[i] = Wl[i]; P.hi[i] = Hl[i]; P.lo[i] = Ll[i];
            P.K[i] = Kl[i]; P.N[i] = Nl[i]; P.kbg[i] = KBl[i];
            P.blk0[i] = acc;
            acc += NPl[i] * KBl[i];          // blocks = npanels*kbg (1024 els each)
        }
        P.blk0[8] = acc;                      // 3176
        prep_all<<<dim3(acc), blk, 0, stream>>>(P);
    }

    // ---- encoder: split-bf16 (3-MFMA) ----
    gemm_mfma<1, true, 2><<<dim3(8, 128), blk, 0, stream>>>(Xhi, Xlo, Wt1h, Wt1l, b1, nullptr, h1h, h1l, 100, 25, 1000);
    gemm_mfma<1, true, 2><<<dim3(4, 128), blk, 0, stream>>>(h1h, h1l, Wt2h, Wt2l, b2, nullptr, h2h, h2l, 128, 32, 500);
    gemm_mfma<1, true, 2><<<dim3(3, 128), blk, 0, stream>>>(h2h, h2l, Wt3h, Wt3l, b3, nullptr, h3h, h3l, 64, 16, 300);
    gemm_mfma<0, true, 0><<<dim3(1, 128), blk, 0, stream>>>(h3h, h3l, Wt4h, Wt4l, b4, Zenc, nullptr, nullptr, 48, 12, 64);

    // ---- fused nearest-neighbor (no S matrix) ----
    row_norms64<<<dim3(8), dim3(64), 0, stream>>>(E, En2, 512);
    fused_nn<<<dim3(256), blk, 0, stream>>>(Zenc, E, En2, Zdec, Zdcb, Pv, Pi);
    argmin_cols_p2<<<dim3(512), blk, 0, stream>>>(Pv, Pi, Zenc, Zemb);

    // ---- decoder: plain bf16 MFMA ----
    gemm_mfma<2, false, 1><<<dim3(3, 128), blk, 0, stream>>>(Zdcb, nullptr, Vt1, nullptr, c1, nullptr, g1, nullptr, 8, 2, 300);
    gemm_mfma<2, false, 1><<<dim3(4, 128), blk, 0, stream>>>(g1, nullptr, Vt2, nullptr, c2, nullptr, g2, nullptr, 48, 12, 500);
    gemm_mfma<2, false, 1><<<dim3(8, 128), blk, 0, stream>>>(g2, nullptr, Vt3, nullptr, c3, nullptr, g3, nullptr, 64, 16, 1000);
    gemm_mfma<3, false, 0><<<dim3(7, 128), blk, 0, stream>>>(g3, nullptr, Vt4, nullptr, c4, Xrec, nullptr, nullptr, 128, 32, 784);
}

// Round 10
// 537.000 us; speedup vs baseline: 1.2916x; 1.2916x over previous
//
#include <hip/hip_runtime.h>
#include <hip/hip_bf16.h>

// ---------------------------------------------------------------------------
// VQ-VAE forward. Round 10: revert to the proven round-6 pipeline (3-MFMA
// split-bf16 encoder — round 9's K-concat dropped the AhBl/AlBh cross terms
// and broke argmin fidelity) + round-8's verified prep_all merge.
// Tiled operand layout [panel][kbg][128][8], staged via global_load_lds x16.
// ---------------------------------------------------------------------------

typedef __attribute__((ext_vector_type(8))) short short8v;
typedef __attribute__((ext_vector_type(4))) float f32x4;

__device__ inline ushort f2bf(float v) {
    __hip_bfloat16 h = __float2bfloat16(v);
    return *reinterpret_cast<ushort*>(&h);
}
__device__ inline float bf2f(ushort s) {
    __hip_bfloat16 h;
    *reinterpret_cast<ushort*>(&h) = s;
    return __bfloat162float(h);
}

// copy 8192 B (one K-step tile) global -> LDS; layouts identical (linear DMA).
__device__ __forceinline__ void stage_tile(const ushort* __restrict__ src,
                                           ushort* dst, int wid, int lane)
{
#pragma unroll
    for (int j = 0; j < 2; ++j) {
        const int ci = (j << 2) + wid;
        __builtin_amdgcn_global_load_lds(
            (const __attribute__((address_space(1))) unsigned int*)(src + ci * 512 + lane * 8),
            (__attribute__((address_space(3))) unsigned int*)(dst + ci * 512),
            16, 0, 0);
    }
}

// ---------------------------------------------------------------------------
// MFMA GEMM on tiled operands. A: [rb][kbgA][128][8] (+lo if SPLIT),
// B: [cb][kbgA][128][8] (+lo). nsteps = kbgA/4.
// SPLIT: acc += Ah*Bh + Ah*Bl + Al*Bh  (f32-class accuracy for argmin).
// OMODE 0: f32 row-major out. OMODE 1: bf16 tiled out. OMODE 2: split tiled.
// ACT: 0 none, 1 relu, 2 leaky(0.1), 3 tanh
// ---------------------------------------------------------------------------
template<int ACT, bool SPLIT, int OMODE>
__global__ __launch_bounds__(256)
void gemm_mfma(const ushort* __restrict__ At, const ushort* __restrict__ Alt,
               const ushort* __restrict__ Bt, const ushort* __restrict__ Blt,
               const float* __restrict__ bias,
               float* __restrict__ Cf, ushort* __restrict__ Chi, ushort* __restrict__ Clo,
               int kbgA, int nsteps, int N)
{
    __shared__ short8v AhV[512];                       // 8192 B
    __shared__ short8v BhV[512];
    __shared__ short8v AlV[SPLIT ? 512 : 1];
    __shared__ short8v BlV[SPLIT ? 512 : 1];
    ushort* Ah = (ushort*)AhV;
    ushort* Bh = (ushort*)BhV;
    ushort* Al = (ushort*)AlV;
    ushort* Bl = (ushort*)BlV;

    const int tid  = threadIdx.x;
    const int lane = tid & 63;
    const int wid  = tid >> 6;
    const int wr   = (wid >> 1) * 64;
    const int wc   = (wid & 1) * 64;

    // XCD-aware bijective swizzle (gridDim.y == 128 => nwg % 8 == 0)
    const int flat = blockIdx.y * gridDim.x + blockIdx.x;
    const int cpx  = (gridDim.x * gridDim.y) >> 3;
    const int swz  = (flat & 7) * cpx + (flat >> 3);
    const int cb   = swz % gridDim.x;
    const int rb   = swz / gridDim.x;
    const int row0 = rb * 128;
    const int col0 = cb * 128;

    f32x4 acc[4][4];
#pragma unroll
    for (int m = 0; m < 4; ++m)
#pragma unroll
        for (int n = 0; n < 4; ++n) acc[m][n] = (f32x4){0.f, 0.f, 0.f, 0.f};

    const int fr = lane & 15;
    const int kq = lane >> 4;

    const size_t abase = (size_t)rb * kbgA * 1024;
    const size_t bbase = (size_t)cb * kbgA * 1024;

    for (int s = 0; s < nsteps; ++s) {
        const size_t off = (size_t)s * 4096;
        stage_tile(At + abase + off, Ah, wid, lane);
        stage_tile(Bt + bbase + off, Bh, wid, lane);
        if (SPLIT) {
            stage_tile(Alt + abase + off, Al, wid, lane);
            stage_tile(Blt + bbase + off, Bl, wid, lane);
        }
        __syncthreads();   // compiler drains vmcnt(0) here (m97 structure)

        short8v a_h[4], b_h[4], a_l[4], b_l[4];
#pragma unroll
        for (int m = 0; m < 4; ++m) {
            a_h[m] = *(const short8v*)&Ah[kq * 1024 + (wr + m * 16 + fr) * 8];
            if (SPLIT) a_l[m] = *(const short8v*)&Al[kq * 1024 + (wr + m * 16 + fr) * 8];
        }
#pragma unroll
        for (int n = 0; n < 4; ++n) {
            b_h[n] = *(const short8v*)&Bh[kq * 1024 + (wc + n * 16 + fr) * 8];
            if (SPLIT) b_l[n] = *(const short8v*)&Bl[kq * 1024 + (wc + n * 16 + fr) * 8];
        }
#pragma unroll
        for (int m = 0; m < 4; ++m)
#pragma unroll
            for (int n = 0; n < 4; ++n) {
                acc[m][n] = __builtin_amdgcn_mfma_f32_16x16x32_bf16(a_h[m], b_h[n], acc[m][n], 0, 0, 0);
                if (SPLIT) {
                    acc[m][n] = __builtin_amdgcn_mfma_f32_16x16x32_bf16(a_h[m], b_l[n], acc[m][n], 0, 0, 0);
                    acc[m][n] = __builtin_amdgcn_mfma_f32_16x16x32_bf16(a_l[m], b_h[n], acc[m][n], 0, 0, 0);
                }
            }
        __syncthreads();
    }

    // epilogue: C/D layout col=lane&15, row=(lane>>4)*4+reg
    const int kbgN = gridDim.x << 4;   // output tiled kbg (Npad/8)
#pragma unroll
    for (int n = 0; n < 4; ++n) {
        const int c = col0 + wc + n * 16 + fr;
        const float bv = (bias && c < N) ? bias[c] : 0.f;
#pragma unroll
        for (int m = 0; m < 4; ++m) {
#pragma unroll
            for (int i = 0; i < 4; ++i) {
                const int r = row0 + wr + m * 16 + kq * 4 + i;
                float v = acc[m][n][i] + bv;
                if (ACT == 1) v = fmaxf(v, 0.f);
                else if (ACT == 2) v = (v > 0.f) ? v : 0.1f * v;
                else if (ACT == 3) v = tanhf(v);
                if (OMODE == 0) {
                    if (c < N) Cf[(size_t)r * N + c] = v;
                } else {
                    if (c >= N) v = 0.f;   // zero the col-pad region
                    const size_t oi = (((size_t)(r >> 7) * kbgN + (c >> 3)) * 128 + (r & 127)) * 8 + (c & 7);
                    const ushort h = f2bf(v);
                    Chi[oi] = h;
                    if (OMODE == 2) Clo[oi] = f2bf(v - bf2f(h));
                }
            }
        }
    }
}

// ---------------------------------------------------------------------------
// f32 VALU GEMM for S = Zenc @ E^T (argmin needs f32 fidelity; ~1 GF)
// ---------------------------------------------------------------------------
__global__ __launch_bounds__(256)
void gemm_f32_bt(const float* __restrict__ A, const float* __restrict__ W,
                 float* __restrict__ C, int M, int K, int N)
{
    __shared__ float As[16][68];
    __shared__ float Ws[16][68];

    const int tid = threadIdx.x;
    const int tx = tid & 15, ty = tid >> 4;
    const int row0 = blockIdx.y * 64, col0 = blockIdx.x * 64;

    float acc[4][4];
#pragma unroll
    for (int i = 0; i < 4; ++i)
#pragma unroll
        for (int j = 0; j < 4; ++j) acc[i][j] = 0.f;

    const int a_row = tid >> 2, a_k4 = (tid & 3) << 2;
    const int t_col = tid >> 2, t_k4 = (tid & 3) << 2;

    for (int k0 = 0; k0 < K; k0 += 16) {
        {
            const int gr = row0 + a_row, gk = k0 + a_k4;
            float4 av = *reinterpret_cast<const float4*>(A + (size_t)gr * K + gk);
            As[a_k4 + 0][a_row] = av.x; As[a_k4 + 1][a_row] = av.y;
            As[a_k4 + 2][a_row] = av.z; As[a_k4 + 3][a_row] = av.w;
        }
        {
            const int gc = col0 + t_col, gk = k0 + t_k4;
            float4 wv = *reinterpret_cast<const float4*>(W + (size_t)gc * K + gk);
            Ws[t_k4 + 0][t_col] = wv.x; Ws[t_k4 + 1][t_col] = wv.y;
            Ws[t_k4 + 2][t_col] = wv.z; Ws[t_k4 + 3][t_col] = wv.w;
        }
        __syncthreads();
#pragma unroll
        for (int kk = 0; kk < 16; ++kk) {
            float4 a = *reinterpret_cast<const float4*>(&As[kk][ty << 2]);
            float4 w = *reinterpret_cast<const float4*>(&Ws[kk][tx << 2]);
            acc[0][0] += a.x * w.x; acc[0][1] += a.x * w.y; acc[0][2] += a.x * w.z; acc[0][3] += a.x * w.w;
            acc[1][0] += a.y * w.x; acc[1][1] += a.y * w.y; acc[1][2] += a.y * w.z; acc[1][3] += a.y * w.w;
            acc[2][0] += a.z * w.x; acc[2][1] += a.z * w.y; acc[2][2] += a.z * w.z; acc[2][3] += a.z * w.w;
            acc[3][0] += a.w * w.x; acc[3][1] += a.w * w.y; acc[3][2] += a.w * w.z; acc[3][3] += a.w * w.w;
        }
        __syncthreads();
    }
#pragma unroll
    for (int i = 0; i < 4; ++i) {
        const int r = row0 + (ty << 2) + i;
#pragma unroll
        for (int j = 0; j < 4; ++j) {
            const int c = col0 + (tx << 2) + j;
            C[(size_t)r * N + c] = acc[i][j];
        }
    }
}

__global__ void row_norms64(const float* __restrict__ X, float* __restrict__ out, int rows)
{
    int r = blockIdx.x * blockDim.x + threadIdx.x;
    if (r >= rows) return;
    const float* p = X + (size_t)r * 64;
    float s = 0.f;
#pragma unroll
    for (int i = 0; i < 16; ++i) {
        float4 v = *reinterpret_cast<const float4*>(p + i * 4);
        s += v.x * v.x + v.y * v.y + v.z * v.z + v.w * v.w;
    }
    out[r] = s;
}

// row argmin over 512 codebook entries; gather E row -> Zdec (f32) and
// tiled-bf16 Zdcb (kbg=8) for the decoder's first MFMA GEMM.
__global__ __launch_bounds__(256)
void argmin_rows(const float* __restrict__ S, const float* __restrict__ En2,
                 const float* __restrict__ E, float* __restrict__ Zdec,
                 ushort* __restrict__ Zdcb)
{
    const int wave = (blockIdx.x * blockDim.x + threadIdx.x) >> 6;
    const int lane = threadIdx.x & 63;
    if (wave >= 16384) return;
    const float* Srow = S + (size_t)wave * 512;
    float best = INFINITY;
    int bidx = 0x7fffffff;
    for (int k = lane; k < 512; k += 64) {
        float v = En2[k] - 2.0f * Srow[k];
        if (v < best) { best = v; bidx = k; }
    }
#pragma unroll
    for (int off = 32; off > 0; off >>= 1) {
        float ov = __shfl_down(best, off);
        int   oi = __shfl_down(bidx, off);
        if (ov < best || (ov == best && oi < bidx)) { best = ov; bidx = oi; }
    }
    bidx = __shfl(bidx, 0);
    const float val = E[(size_t)bidx * 64 + lane];
    Zdec[(size_t)wave * 64 + lane] = val;
    const size_t oi = (((size_t)(wave >> 7) * 8 + (lane >> 3)) * 128 + (wave & 127)) * 8 + (lane & 7);
    Zdcb[oi] = f2bf(val);
}

// column argmin phase 1: block g scans rows [64g, 64g+64); thread tid tracks
// cols tid and tid+256 (coalesced). Partials -> [col][g].
__global__ __launch_bounds__(256)
void argmin_cols_p1(const float* __restrict__ S, const float* __restrict__ Zn2,
                    float* __restrict__ pval, int* __restrict__ pidx)
{
    const int g   = blockIdx.x;
    const int tid = threadIdx.x;
    const int r0  = g << 6;
    float b0 = INFINITY, b1 = INFINITY;
    int   i0 = 0, i1 = 0;
    for (int r = 0; r < 64; ++r) {
        const float zn = Zn2[r0 + r];
        const float* row = S + (size_t)(r0 + r) * 512;
        const float v0 = zn - 2.0f * row[tid];
        const float v1 = zn - 2.0f * row[tid + 256];
        if (v0 < b0) { b0 = v0; i0 = r0 + r; }   // ascending r: first-min kept
        if (v1 < b1) { b1 = v1; i1 = r0 + r; }
    }
    pval[(size_t)tid * 256 + g]         = b0;
    pidx[(size_t)tid * 256 + g]         = i0;
    pval[(size_t)(tid + 256) * 256 + g] = b1;
    pidx[(size_t)(tid + 256) * 256 + g] = i1;
}

__global__ __launch_bounds__(256)
void argmin_cols_p2(const float* __restrict__ pval, const int* __restrict__ pidx,
                    const float* __restrict__ Zenc, float* __restrict__ Zemb)
{
    const int k   = blockIdx.x;
    const int tid = threadIdx.x;
    float v = pval[(size_t)k * 256 + tid];
    int   i = pidx[(size_t)k * 256 + tid];
    __shared__ float vs[256];
    __shared__ int   is_[256];
    vs[tid] = v; is_[tid] = i;
    __syncthreads();
    for (int s = 128; s > 0; s >>= 1) {
        if (tid < s) {
            if (vs[tid + s] < vs[tid] ||
                (vs[tid + s] == vs[tid] && is_[tid + s] < is_[tid])) {
                vs[tid] = vs[tid + s]; is_[tid] = is_[tid + s];
            }
        }
        __syncthreads();
    }
    const int idx = is_[0];
    if (tid < 64) Zemb[(size_t)k * 64 + tid] = Zenc[(size_t)idx * 64 + tid];
}

// X [16384][784] f32 -> tiled split bf16 [128 rb][100 kbg][128][8], k-pad zero
__global__ void conv_x(const float* __restrict__ X, ushort* __restrict__ hi,
                       ushort* __restrict__ lo)
{
    const long total = 128L * 100 * 1024;
    for (long idx = blockIdx.x * 256L + threadIdx.x; idx < total; idx += (long)gridDim.x * 256L) {
        const int j  = (int)(idx & 7);
        const long t = idx >> 3;
        const int rn = (int)(t & 127);
        const long u = t >> 7;
        const int kb = (int)(u % 100);
        const int rb = (int)(u / 100);
        const int r = rb * 128 + rn;
        const int k = kb * 8 + j;
        const float v = (k < 784) ? X[(size_t)r * 784 + k] : 0.f;
        const ushort h = f2bf(v);
        hi[idx] = h;
        lo[idx] = f2bf(v - bf2f(h));
    }
}

// ---------------------------------------------------------------------------
// merged weight prep: 8 segments (W1..W4 split hi/lo, V1..V4 plain) in one
// launch. One block = 1024 elements (256 thr x ushort4).
// ---------------------------------------------------------------------------
struct PrepAll {
    const float* W[8];
    ushort* hi[8];
    ushort* lo[8];
    int K[8], N[8], kbg[8];
    int blk0[9];
};

__global__ __launch_bounds__(256)
void prep_all(PrepAll P)
{
    const int bid = blockIdx.x;
    int s = 0;
#pragma unroll
    for (int i = 1; i < 8; ++i) if (bid >= P.blk0[i]) s = i;
    const int  K = P.K[s], N = P.N[s], kbg = P.kbg[s];
    const bool split = (s < 4);
    const float* W = P.W[s];
    ushort* hi = P.hi[s];
    ushort* lo = P.lo[s];

    const long idx = (long)(bid - P.blk0[s]) * 1024 + threadIdx.x * 4;
    const int j0 = (int)(idx & 7);
    const long t = idx >> 3;
    const int cn = (int)(t & 127);
    const long u = t >> 7;
    const int kb = (int)(u % kbg);
    const int p  = (int)(u / kbg);
    const int n  = p * 128 + cn;

    ushort hv[4], lv[4];
#pragma unroll
    for (int e = 0; e < 4; ++e) {
        const int k = kb * 8 + j0 + e;
        const float v = (k < K && n < N) ? W[(size_t)k * N + n] : 0.f;
        const ushort h = f2bf(v);
        hv[e] = h;
        lv[e] = f2bf(v - bf2f(h));
    }
    *(ushort4*)&hi[idx] = *(ushort4*)hv;
    if (split) *(ushort4*)&lo[idx] = *(ushort4*)lv;
}

extern "C" void kernel_launch(void* const* d_in, const int* in_sizes, int n_in,
                              void* d_out, int out_size, void* d_ws, size_t ws_size,
                              hipStream_t stream)
{
    const float* X  = (const float*)d_in[0];
    const float* W1 = (const float*)d_in[1];
    const float* b1 = (const float*)d_in[2];
    const float* W2 = (const float*)d_in[3];
    const float* b2 = (const float*)d_in[4];
    const float* W3 = (const float*)d_in[5];
    const float* b3 = (const float*)d_in[6];
    const float* W4 = (const float*)d_in[7];
    const float* b4 = (const float*)d_in[8];
    const float* E  = (const float*)d_in[9];
    const float* V1 = (const float*)d_in[10];
    const float* c1 = (const float*)d_in[11];
    const float* V2 = (const float*)d_in[12];
    const float* c2 = (const float*)d_in[13];
    const float* V3 = (const float*)d_in[14];
    const float* c3 = (const float*)d_in[15];
    const float* V4 = (const float*)d_in[16];
    const float* c4 = (const float*)d_in[17];

    float* out  = (float*)d_out;
    float* Xrec = out;                  // 16384*784
    float* Zenc = out + 12845056;
    float* Zdec = out + 13893632;
    float* Zemb = out + 14942208;

    // ---- workspace layout (peak ~98.9 MB; >=118 MB proven) ----
    char* ws = (char*)d_ws;
    ushort* Xhi = (ushort*)(ws + 0);           // 26,214,400
    ushort* Xlo = (ushort*)(ws + 26214400);    // -> 52,428,800
    ushort* h2h = (ushort*)(ws + 0);           // after enc1
    ushort* h2l = (ushort*)(ws + 16777216);
    float*  S   = (float*)(ws + 0);            // after enc3 (33.5 MB)
    ushort* g3  = (ushort*)(ws + 0);           // after argmins
    ushort* h1l = (ushort*)(ws + 52428800);    // 33,554,432
    ushort* h3h = (ushort*)(ws + 52428800);    // after enc2
    ushort* h3l = (ushort*)(ws + 65011712);
    ushort* g1  = (ushort*)(ws + 52428800);    // after enc4
    ushort* g2  = (ushort*)(ws + 65011712);
    ushort* h1h = (ushort*)d_out;              // parks in Xrec slab (dead before dec4)
    float*  Zn2  = (float*)(ws + 85983232);
    float*  En2  = (float*)(ws + 86048768);
    ushort* Zdcb = (ushort*)(ws + 86050816);   // 2,097,152
    ushort* Wt1h = (ushort*)(ws + 88147968);   // 8p x 100kbg
    ushort* Wt1l = (ushort*)(ws + 89786368);
    ushort* Wt2h = (ushort*)(ws + 91424768);   // 4p x 128
    ushort* Wt2l = (ushort*)(ws + 92473344);
    ushort* Wt3h = (ushort*)(ws + 93521920);   // 3p x 64
    ushort* Wt3l = (ushort*)(ws + 93915136);
    ushort* Wt4h = (ushort*)(ws + 94308352);   // 1p x 48
    ushort* Wt4l = (ushort*)(ws + 94406656);
    ushort* Vt1  = (ushort*)(ws + 94504960);   // 3p x 8
    ushort* Vt2  = (ushort*)(ws + 94554112);   // 4p x 48
    ushort* Vt3  = (ushort*)(ws + 94947328);   // 8p x 64
    ushort* Vt4  = (ushort*)(ws + 95995904);   // 7p x 128 -> 97,830,912
    float*  Pv   = (float*)(ws + 97830912);    // [512][256]
    int*    Pi   = (int*)  (ws + 98355200);    // -> 98,879,488

    const dim3 blk(256);

    // ---- conversion & tiling ----
    conv_x<<<dim3(2048), blk, 0, stream>>>(X, Xhi, Xlo);
    {
        PrepAll P;
        const float* Wl[8] = {W1, W2, W3, W4, V1, V2, V3, V4};
        ushort* Hl[8] = {Wt1h, Wt2h, Wt3h, Wt4h, Vt1, Vt2, Vt3, Vt4};
        ushort* Ll[8] = {Wt1l, Wt2l, Wt3l, Wt4l, nullptr, nullptr, nullptr, nullptr};
        const int Kl[8]   = {784, 1000, 500, 300, 64, 300, 500, 1000};
        const int Nl[8]   = {1000, 500, 300, 64, 300, 500, 1000, 784};
        const int KBl[8]  = {100, 128, 64, 48, 8, 48, 64, 128};
        const int NPl[8]  = {8, 4, 3, 1, 3, 4, 8, 7};
        int acc = 0;
        for (int i = 0; i < 8; ++i) {
            P.W[i] = Wl[i]; P.hi[i] = Hl[i]; P.lo[i] = Ll[i];
            P.K[i] = Kl[i]; P.N[i] = Nl[i]; P.kbg[i] = KBl[i];
            P.blk0[i] = acc;
            acc += NPl[i] * KBl[i];          // blocks = npanels*kbg
        }
        P.blk0[8] = acc;                      // 3176
        prep_all<<<dim3(acc), blk, 0, stream>>>(P);
    }

    // ---- encoder: split-bf16 (3-MFMA) ----
    gemm_mfma<1, true, 2><<<dim3(8, 128), blk, 0, stream>>>(Xhi, Xlo, Wt1h, Wt1l, b1, nullptr, h1h, h1l, 100, 25, 1000);
    gemm_mfma<1, true, 2><<<dim3(4, 128), blk, 0, stream>>>(h1h, h1l, Wt2h, Wt2l, b2, nullptr, h2h, h2l, 128, 32, 500);
    gemm_mfma<1, true, 2><<<dim3(3, 128), blk, 0, stream>>>(h2h, h2l, Wt3h, Wt3l, b3, nullptr, h3h, h3l, 64, 16, 300);
    gemm_mfma<0, true, 0><<<dim3(1, 128), blk, 0, stream>>>(h3h, h3l, Wt4h, Wt4l, b4, Zenc, nullptr, nullptr, 48, 12, 64);

    // ---- nearest-neighbor (f32, proven chain) ----
    row_norms64<<<dim3(8),  dim3(64), 0, stream>>>(E,    En2, 512);
    row_norms64<<<dim3(64), blk,      0, stream>>>(Zenc, Zn2, 16384);
    gemm_f32_bt<<<dim3(8, 256), blk, 0, stream>>>(Zenc, E, S, 16384, 64, 512);
    argmin_rows<<<dim3(4096), blk, 0, stream>>>(S, En2, E, Zdec, Zdcb);
    argmin_cols_p1<<<dim3(256), blk, 0, stream>>>(S, Zn2, Pv, Pi);
    argmin_cols_p2<<<dim3(512), blk, 0, stream>>>(Pv, Pi, Zenc, Zemb);

    // ---- decoder: plain bf16 MFMA ----
    gemm_mfma<2, false, 1><<<dim3(3, 128), blk, 0, stream>>>(Zdcb, nullptr, Vt1, nullptr, c1, nullptr, g1, nullptr, 8, 2, 300);
    gemm_mfma<2, false, 1><<<dim3(4, 128), blk, 0, stream>>>(g1, nullptr, Vt2, nullptr, c2, nullptr, g2, nullptr, 48, 12, 500);
    gemm_mfma<2, false, 1><<<dim3(8, 128), blk, 0, stream>>>(g2, nullptr, Vt3, nullptr, c3, nullptr, g3, nullptr, 64, 16, 1000);
    gemm_mfma<3, false, 0><<<dim3(7, 128), blk, 0, stream>>>(g3, nullptr, Vt4, nullptr, c4, Xrec, nullptr, nullptr, 128, 32, 784);
}